// Round 1
// baseline (171.189 us; speedup 1.0000x reference)
//
#include <hip/hip_runtime.h>

#define B_      2048
#define SYN     128
#define SEM     256
#define IN_DIM  647
#define K1      704      // 647 padded to 11*64
#define HIDDEN  1024
#define OUT_N   10000
#define OUT_PAD 10112    // 79*128
#define NNZ     8

typedef __bf16 bf16x8 __attribute__((ext_vector_type(8)));
typedef float  f32x4  __attribute__((ext_vector_type(4)));

__device__ __forceinline__ unsigned short f2b(float v) {
    __bf16 b = (__bf16)v;
    return __builtin_bit_cast(unsigned short, b);
}

// ---------------------------------------------------------------- build x ---
// x row layout (K1=704 bf16): [0:128) cat_embed, [128:384) hvb_embed,
// [384:640) hvf_embed, [640:647) d_onehot, [647:704) zero pad.
__global__ __launch_bounds__(256) void build_x(
    const float* __restrict__ d_onehot,
    const int*   __restrict__ cat_ix,
    const int*   __restrict__ hvb_ix,
    const int*   __restrict__ hvf_ix,
    const float* __restrict__ hvb_top,
    const float* __restrict__ hvf_top,
    const float* __restrict__ cat_embeds,
    const float* __restrict__ hvec_embeds,
    unsigned short* __restrict__ xb)
{
    const int b = blockIdx.x, t = threadIdx.x;
    unsigned short* xrow = xb + (size_t)b * K1;

    if (t < SYN) {
        int c = cat_ix[b];
        xrow[t] = f2b(cat_embeds[(size_t)c * SYN + t]);
    }
    // hvb: each of 256 threads owns one SEM column; dedup indices (set semantics)
    {
        int ix[NNZ];
        #pragma unroll
        for (int j = 0; j < NNZ; ++j) ix[j] = hvb_ix[b * NNZ + j];
        float s = hvb_top[(size_t)b * SEM + t];
        #pragma unroll
        for (int j = 0; j < NNZ; ++j) {
            bool dup = false;
            for (int k2 = 0; k2 < j; ++k2) dup = dup || (ix[j] == ix[k2]);
            if (!dup) s += hvec_embeds[(size_t)ix[j] * SEM + t];
        }
        xrow[SYN + t] = f2b(s);
    }
    {
        int ix[NNZ];
        #pragma unroll
        for (int j = 0; j < NNZ; ++j) ix[j] = hvf_ix[b * NNZ + j];
        float s = hvf_top[(size_t)b * SEM + t];
        #pragma unroll
        for (int j = 0; j < NNZ; ++j) {
            bool dup = false;
            for (int k2 = 0; k2 < j; ++k2) dup = dup || (ix[j] == ix[k2]);
            if (!dup) s += hvec_embeds[(size_t)ix[j] * SEM + t];
        }
        xrow[SYN + SEM + t] = f2b(s);
    }
    if (t < 7)       xrow[640 + t] = f2b(d_onehot[b * 7 + t]);
    else if (t < 64) xrow[640 + t] = 0;   // cols 647..703 zero
}

// ------------------------------------------------------------ weight casts ---
__global__ void cvt_w1(const float* __restrict__ W1, unsigned short* __restrict__ W1b) {
    int idx = blockIdx.x * 256 + threadIdx.x;
    if (idx >= HIDDEN * K1) return;
    int r = idx / K1, c = idx - r * K1;
    W1b[idx] = f2b(c < IN_DIM ? W1[r * IN_DIM + c] : 0.f);
}

__global__ void cvt_w2(const float* __restrict__ W2, unsigned short* __restrict__ W2b) {
    size_t idx = (size_t)blockIdx.x * 256 + threadIdx.x;
    float v = (idx < (size_t)OUT_N * HIDDEN) ? W2[idx] : 0.f;
    W2b[idx] = f2b(v);
}

// ------------------------------------------------------------------- GEMM ---
// C = A(M,K) @ B(N,K)^T, bf16 inputs, fp32 accumulate. 128x128 tile, BK=64,
// 4 waves (2x2), each wave 64x64 via 4x4 16x16x32 MFMA frags (m97 structure).
// MODE 0: +bias, relu, store bf16 (stride N). MODE 1: +bias, store fp32
// (stride nvalid), guard col < nvalid.
template<int MODE>
__global__ __launch_bounds__(256) void gemm_bt(
    const unsigned short* __restrict__ A,
    const unsigned short* __restrict__ Bm,
    const float* __restrict__ bias,
    void* __restrict__ outp,
    int K, int N, int nvalid)
{
    __shared__ __align__(16) unsigned short lds_a[128 * 64];
    __shared__ __align__(16) unsigned short lds_b[128 * 64];
    const int tid = threadIdx.x;
    const int wv = tid >> 6, ln = tid & 63;
    const int wr = wv >> 1, wc = wv & 1;
    const int m0 = blockIdx.x * 128, n0 = blockIdx.y * 128;
    const int lr = ln & 15, lh = ln >> 4;

    f32x4 acc[4][4];
    {
        f32x4 z = {0.f, 0.f, 0.f, 0.f};
        #pragma unroll
        for (int i = 0; i < 4; ++i)
            #pragma unroll
            for (int j = 0; j < 4; ++j) acc[i][j] = z;
    }

    for (int kt = 0; kt < K; kt += 64) {
        // ---- stage 128x64 A and B tiles via global_load_lds (16B/lane) ----
        #pragma unroll
        for (int i = 0; i < 4; ++i) {
            int c   = i * 256 + tid;     // 16B chunk id, 1024 chunks per tile
            int row = c >> 3, cc = c & 7;
            const unsigned short* ga = A  + (size_t)(m0 + row) * K + kt + cc * 8;
            const unsigned short* gb = Bm + (size_t)(n0 + row) * K + kt + cc * 8;
            unsigned short* la = &lds_a[(size_t)(i * 256 + wv * 64) * 8]; // wave-uniform base
            unsigned short* lb = &lds_b[(size_t)(i * 256 + wv * 64) * 8];
            __builtin_amdgcn_global_load_lds((__attribute__((address_space(1))) void*)ga,
                                             (__attribute__((address_space(3))) void*)la, 16, 0, 0);
            __builtin_amdgcn_global_load_lds((__attribute__((address_space(1))) void*)gb,
                                             (__attribute__((address_space(3))) void*)lb, 16, 0, 0);
        }
        __syncthreads();   // compiler drains vmcnt before barrier

        #pragma unroll
        for (int ks = 0; ks < 2; ++ks) {
            bf16x8 af[4], bfr[4];
            #pragma unroll
            for (int mi = 0; mi < 4; ++mi)
                af[mi] = *(const bf16x8*)&lds_a[(wr * 64 + mi * 16 + lr) * 64 + ks * 32 + lh * 8];
            #pragma unroll
            for (int ni = 0; ni < 4; ++ni)
                bfr[ni] = *(const bf16x8*)&lds_b[(wc * 64 + ni * 16 + lr) * 64 + ks * 32 + lh * 8];
            #pragma unroll
            for (int mi = 0; mi < 4; ++mi)
                #pragma unroll
                for (int ni = 0; ni < 4; ++ni)
                    acc[mi][ni] = __builtin_amdgcn_mfma_f32_16x16x32_bf16(af[mi], bfr[ni], acc[mi][ni], 0, 0, 0);
        }
        __syncthreads();
    }

    // ---- epilogue; C/D layout: col = ln&15, row = (ln>>4)*4 + r ----
    if (MODE == 0) {
        unsigned short* H = (unsigned short*)outp;
        #pragma unroll
        for (int mi = 0; mi < 4; ++mi)
            #pragma unroll
            for (int ni = 0; ni < 4; ++ni) {
                int col = n0 + wc * 64 + ni * 16 + lr;
                float bb = bias[col];
                #pragma unroll
                for (int r = 0; r < 4; ++r) {
                    int row = m0 + wr * 64 + mi * 16 + lh * 4 + r;
                    float v = acc[mi][ni][r] + bb;
                    H[(size_t)row * N + col] = f2b(fmaxf(v, 0.f));
                }
            }
    } else {
        float* O = (float*)outp;
        #pragma unroll
        for (int mi = 0; mi < 4; ++mi)
            #pragma unroll
            for (int ni = 0; ni < 4; ++ni) {
                int col = n0 + wc * 64 + ni * 16 + lr;
                if (col < nvalid) {
                    float bb = bias[col];
                    #pragma unroll
                    for (int r = 0; r < 4; ++r) {
                        int row = m0 + wr * 64 + mi * 16 + lh * 4 + r;
                        O[(size_t)row * nvalid + col] = acc[mi][ni][r] + bb;
                    }
                }
            }
    }
}

// ------------------------------------------------------- in-place logsoftmax ---
__global__ __launch_bounds__(256) void lsm(float* __restrict__ out) {
    __shared__ __align__(16) float rowbuf[OUT_N];
    __shared__ float red[8];
    const int t = threadIdx.x, wv = t >> 6, ln = t & 63;
    float* o = out + (size_t)blockIdx.x * OUT_N;

    float mx = -3.4e38f;
    for (int i = t; i < OUT_N; i += 256) {
        float v = o[i];
        rowbuf[i] = v;
        mx = fmaxf(mx, v);
    }
    #pragma unroll
    for (int off = 32; off > 0; off >>= 1) mx = fmaxf(mx, __shfl_xor(mx, off, 64));
    if (ln == 0) red[wv] = mx;
    __syncthreads();
    float m4 = fmaxf(fmaxf(red[0], red[1]), fmaxf(red[2], red[3]));

    float s = 0.f;
    for (int i = t; i < OUT_N; i += 256) s += __expf(rowbuf[i] - m4);
    #pragma unroll
    for (int off = 32; off > 0; off >>= 1) s += __shfl_xor(s, off, 64);
    if (ln == 0) red[4 + wv] = s;
    __syncthreads();
    float lz = m4 + logf(red[4] + red[5] + red[6] + red[7]);

    for (int i = t; i < OUT_N; i += 256) o[i] = rowbuf[i] - lz;
}

// ----------------------------------------------------------------- launch ---
extern "C" void kernel_launch(void* const* d_in, const int* in_sizes, int n_in,
                              void* d_out, int out_size, void* d_ws, size_t ws_size,
                              hipStream_t stream) {
    const float* d_onehot    = (const float*)d_in[0];
    const int*   cat_ix      = (const int*)  d_in[1];
    const int*   hvb_ix      = (const int*)  d_in[2];
    const int*   hvf_ix      = (const int*)  d_in[3];
    const float* hvb_top     = (const float*)d_in[4];
    const float* hvf_top     = (const float*)d_in[5];
    const float* cat_embeds  = (const float*)d_in[6];
    const float* hvec_embeds = (const float*)d_in[7];
    const float* W1          = (const float*)d_in[8];
    const float* b1          = (const float*)d_in[9];
    const float* W2          = (const float*)d_in[10];
    const float* b2          = (const float*)d_in[11];
    float* out = (float*)d_out;

    // workspace carve (bf16 buffers), total ~27.9 MB
    unsigned short* xb  = (unsigned short*)d_ws;               // 2048 x 704
    unsigned short* W1b = xb  + (size_t)B_ * K1;               // 1024 x 704
    unsigned short* hB  = W1b + (size_t)HIDDEN * K1;           // 2048 x 1024
    unsigned short* W2b = hB  + (size_t)B_ * HIDDEN;           // 10112 x 1024

    cvt_w1<<<dim3((HIDDEN * K1 + 255) / 256), dim3(256), 0, stream>>>(W1, W1b);
    cvt_w2<<<dim3((OUT_PAD * HIDDEN) / 256), dim3(256), 0, stream>>>(W2, W2b);
    build_x<<<dim3(B_), dim3(256), 0, stream>>>(d_onehot, cat_ix, hvb_ix, hvf_ix,
                                                hvb_top, hvf_top, cat_embeds, hvec_embeds, xb);
    gemm_bt<0><<<dim3(B_ / 128, HIDDEN / 128), dim3(256), 0, stream>>>(
        xb, W1b, b1, (void*)hB, K1, HIDDEN, HIDDEN);
    gemm_bt<1><<<dim3(B_ / 128, OUT_PAD / 128), dim3(256), 0, stream>>>(
        hB, W2b, b2, (void*)out, HIDDEN, 0, OUT_N);
    lsm<<<dim3(B_), dim3(256), 0, stream>>>(out);
}